// Round 5
// baseline (382.980 us; speedup 1.0000x reference)
//
#include <hip/hip_runtime.h>

#define SEQ 512
#define BATCH 128
#define DIM 1024
#define T 32

__device__ __forceinline__ float rlf(float x, int n) {
    return __int_as_float(__builtin_amdgcn_readlane(__float_as_int(x), n));
}

// wave-uniform mask bit: 512 bits in 8 u64 (SGPR-resident), cselect tree + shift
__device__ __forceinline__ int mbit(unsigned long long m0, unsigned long long m1,
        unsigned long long m2, unsigned long long m3, unsigned long long m4,
        unsigned long long m5, unsigned long long m6, unsigned long long m7, int i) {
    int w = i >> 6;
    unsigned long long cm =
        (w < 4) ? ((w < 2) ? (w == 0 ? m0 : m1) : (w == 2 ? m2 : m3))
                : ((w < 6) ? (w == 4 ? m4 : m5) : (w == 6 ? m6 : m7));
    return (int)((cm >> (i & 63)) & 1ULL);
}

#define LOAD_MASKS() \
    unsigned long long m0 = __ballot(mask[(0 * 64 + tid) * BATCH + b] != 0); \
    unsigned long long m1 = __ballot(mask[(1 * 64 + tid) * BATCH + b] != 0); \
    unsigned long long m2 = __ballot(mask[(2 * 64 + tid) * BATCH + b] != 0); \
    unsigned long long m3 = __ballot(mask[(3 * 64 + tid) * BATCH + b] != 0); \
    unsigned long long m4 = __ballot(mask[(4 * 64 + tid) * BATCH + b] != 0); \
    unsigned long long m5 = __ballot(mask[(5 * 64 + tid) * BATCH + b] != 0); \
    unsigned long long m6 = __ballot(mask[(6 * 64 + tid) * BATCH + b] != 0); \
    unsigned long long m7 = __ballot(mask[(7 * 64 + tid) * BATCH + b] != 0);

#define MBIT(i) mbit(m0, m1, m2, m3, m4, m5, m6, m7, (i))

// ---------------- W transpose: Wt[d][t] = W[t][d] ----------------
__global__ void k_wt(const float* __restrict__ W, float* __restrict__ Wt)
{
    int idx = blockIdx.x * 256 + threadIdx.x;   // 32768 total
    if (idx >= DIM * T) return;
    int d = idx >> 5, t = idx & 31;
    Wt[idx] = W[t * DIM + d];
}

// ---------------- emissions (unchanged from round 4) ----------------
__global__ __launch_bounds__(256) void k_emis(const float* __restrict__ A,
        const float* __restrict__ Wt, const float* __restrict__ bias,
        float* __restrict__ e)
{
    __shared__ float lds[64 * 37];
    int tid = threadIdx.x;
    int row0 = blockIdx.x * 64;
    int row = tid & 63;
    int grp = __builtin_amdgcn_readfirstlane(tid >> 6);   // 0..3, wave-uniform
    int q = tid & 7;
    int rb = tid >> 3;

    float acc[8];
    #pragma unroll
    for (int t = 0; t < 8; ++t) acc[t] = bias[grp * 8 + t];

    const float* A0 = &A[(size_t)(row0 + rb) * DIM];
    const float* A1 = &A[(size_t)(row0 + rb + 32) * DIM];

    float4 v0 = *(const float4*)&A0[q * 4];
    float4 v1 = *(const float4*)&A1[q * 4];

    for (int ck = 0; ck < 32; ++ck) {
        lds[rb * 37 + q * 4 + 0] = v0.x;
        lds[rb * 37 + q * 4 + 1] = v0.y;
        lds[rb * 37 + q * 4 + 2] = v0.z;
        lds[rb * 37 + q * 4 + 3] = v0.w;
        lds[(rb + 32) * 37 + q * 4 + 0] = v1.x;
        lds[(rb + 32) * 37 + q * 4 + 1] = v1.y;
        lds[(rb + 32) * 37 + q * 4 + 2] = v1.z;
        lds[(rb + 32) * 37 + q * 4 + 3] = v1.w;
        __syncthreads();
        if (ck < 31) {
            v0 = *(const float4*)&A0[(ck + 1) * 32 + q * 4];
            v1 = *(const float4*)&A1[(ck + 1) * 32 + q * 4];
        }
        #pragma unroll
        for (int d = 0; d < 32; ++d) {
            float av = lds[row * 37 + d];
            const float* wrow = &Wt[(ck * 32 + d) * T + grp * 8];
            #pragma unroll
            for (int t = 0; t < 8; ++t)
                acc[t] = fmaf(av, wrow[t], acc[t]);
        }
        __syncthreads();
    }

    float4* eo = (float4*)&e[(size_t)(row0 + row) * T + grp * 8];
    float4 o0, o1;
    o0.x = acc[0]; o0.y = acc[1]; o0.z = acc[2]; o0.w = acc[3];
    o1.x = acc[4]; o1.y = acc[5]; o1.z = acc[6]; o1.w = acc[7];
    eo[0] = o0; eo[1] = o1;
}

// ---------------- recursions: role 0=alpha(+z), 1=beta, 2=viterbi ----------------
// SGPR mask bitmasks (ballot), tight 8-reg e ring, __expf/__logf, readlane matvec.
__global__ __launch_bounds__(64) void k_rec(const float* __restrict__ e,
        const int* __restrict__ mask,
        const float* __restrict__ trans,
        const float* __restrict__ start,
        const float* __restrict__ endp,
        float* __restrict__ pa, float* __restrict__ pb,
        double* __restrict__ Ca, double* __restrict__ Cb,
        double* __restrict__ zd,
        float* __restrict__ tags_out)
{
    __shared__ unsigned char hist[(SEQ - 1) * T];   // viterbi history (role 2 only)

    int role = blockIdx.x >> 7;     // /128
    int b    = blockIdx.x & 127;
    int tid  = threadIdx.x;
    int j    = tid & 31;            // state (both halves duplicate)

    LOAD_MASKS();

    if (role == 0) {
        // ---- alpha: Et[n] = exp(trans[n][j]) ----
        float Et[32];
        #pragma unroll
        for (int n = 0; n < 32; ++n)
            Et[n] = __expf(trans[n * T + j]);

        float a0 = e[(0 * BATCH + b) * T + j] + start[j];
        float m = a0;
        #pragma unroll
        for (int d = 1; d < 32; d <<= 1) m = fmaxf(m, __shfl_xor(m, d));
        float v = __expf(a0 - m);
        float s = v;
        #pragma unroll
        for (int d = 1; d < 32; d <<= 1) s += __shfl_xor(s, d);
        float p = v / s;
        double C = (double)m + (double)__logf(s);
        if (tid < 32) pa[(size_t)(0 * BATCH + b) * T + j] = p;
        if (tid == 0) Ca[0 * BATCH + b] = C;

        float ef[8];
        #pragma unroll
        for (int u = 0; u < 8; ++u)
            ef[u] = e[(size_t)((1 + u) * BATCH + b) * T + j];

        for (int g = 0; g < 63; ++g) {
            int i0 = 1 + 8 * g;
            #pragma unroll
            for (int u = 0; u < 8; ++u) {
                int i = i0 + u;
                float ee = __expf(ef[u]);
                int inx = i + 8; inx = inx < SEQ ? inx : SEQ - 1;
                ef[u] = e[(size_t)(inx * BATCH + b) * T + j];   // refill slot (8 ahead)
                float q0 = 0.f, q1 = 0.f, q2 = 0.f, q3 = 0.f;
                #pragma unroll
                for (int n = 0; n < 8; ++n) {
                    q0 = fmaf(rlf(p, 4 * n + 0), Et[4 * n + 0], q0);
                    q1 = fmaf(rlf(p, 4 * n + 1), Et[4 * n + 1], q1);
                    q2 = fmaf(rlf(p, 4 * n + 2), Et[4 * n + 2], q2);
                    q3 = fmaf(rlf(p, 4 * n + 3), Et[4 * n + 3], q3);
                }
                float vv = ((q0 + q1) + (q2 + q3)) * ee;
                if (MBIT(i)) p = vv;
                if (tid < 32) pa[(size_t)(i * BATCH + b) * T + j] = p;
                if (tid == 0) Ca[i * BATCH + b] = C;
            }
            float s0 = 0.f, s1 = 0.f, s2 = 0.f, s3 = 0.f;
            #pragma unroll
            for (int n = 0; n < 8; ++n) {
                s0 += rlf(p, 4 * n + 0);
                s1 += rlf(p, 4 * n + 1);
                s2 += rlf(p, 4 * n + 2);
                s3 += rlf(p, 4 * n + 3);
            }
            float ss = (s0 + s1) + (s2 + s3);
            p = p / ss;
            C += (double)__logf(ss);
        }
        // tail i = 505..511 (slots 0..6)
        #pragma unroll
        for (int u = 0; u < 7; ++u) {
            int i = 505 + u;
            float ee = __expf(ef[u]);
            float q0 = 0.f, q1 = 0.f, q2 = 0.f, q3 = 0.f;
            #pragma unroll
            for (int n = 0; n < 8; ++n) {
                q0 = fmaf(rlf(p, 4 * n + 0), Et[4 * n + 0], q0);
                q1 = fmaf(rlf(p, 4 * n + 1), Et[4 * n + 1], q1);
                q2 = fmaf(rlf(p, 4 * n + 2), Et[4 * n + 2], q2);
                q3 = fmaf(rlf(p, 4 * n + 3), Et[4 * n + 3], q3);
            }
            float vv = ((q0 + q1) + (q2 + q3)) * ee;
            if (MBIT(i)) p = vv;
            if (tid < 32) pa[(size_t)(i * BATCH + b) * T + j] = p;
            if (tid == 0) Ca[i * BATCH + b] = C;
        }
        // fused z[b]
        float sz = p * __expf(endp[j]);
        #pragma unroll
        for (int d = 1; d < 32; d <<= 1) sz += __shfl_xor(sz, d);
        if (tid == 0) zd[b] = C + (double)__logf(sz);
    } else if (role == 1) {
        // ---- beta: Et[n] = exp(trans[j][n]) ----
        float Et[32];
        #pragma unroll
        for (int n = 0; n < 32; ++n)
            Et[n] = __expf(trans[j * T + n]);

        float v0 = endp[j];
        float m = v0;
        #pragma unroll
        for (int d = 1; d < 32; d <<= 1) m = fmaxf(m, __shfl_xor(m, d));
        float v = __expf(v0 - m);
        float s = v;
        #pragma unroll
        for (int d = 1; d < 32; d <<= 1) s += __shfl_xor(s, d);
        float p = v / s;
        double C = (double)m + (double)__logf(s);
        if (tid < 32) pb[(size_t)((SEQ - 1) * BATCH + b) * T + j] = p;
        if (tid == 0) Cb[(SEQ - 1) * BATCH + b] = C;

        float ef[8];
        #pragma unroll
        for (int u = 0; u < 8; ++u)
            ef[u] = e[(size_t)((SEQ - 1 - u) * BATCH + b) * T + j];

        for (int g = 0; g < 63; ++g) {
            int i0 = SEQ - 1 - 8 * g;
            #pragma unroll
            for (int u = 0; u < 8; ++u) {
                int i = i0 - u;                       // 511 down to 8
                float ee = __expf(ef[u]);
                int inx = i - 8;                      // >= 0 always
                ef[u] = e[(size_t)(inx * BATCH + b) * T + j];
                float pe = p * ee;
                float q0 = 0.f, q1 = 0.f, q2 = 0.f, q3 = 0.f;
                #pragma unroll
                for (int n = 0; n < 8; ++n) {
                    q0 = fmaf(rlf(pe, 4 * n + 0), Et[4 * n + 0], q0);
                    q1 = fmaf(rlf(pe, 4 * n + 1), Et[4 * n + 1], q1);
                    q2 = fmaf(rlf(pe, 4 * n + 2), Et[4 * n + 2], q2);
                    q3 = fmaf(rlf(pe, 4 * n + 3), Et[4 * n + 3], q3);
                }
                float qq = (q0 + q1) + (q2 + q3);
                if (MBIT(i)) p = qq;
                if (tid < 32) pb[(size_t)((i - 1) * BATCH + b) * T + j] = p;
                if (tid == 0) Cb[(i - 1) * BATCH + b] = C;
            }
            float s0 = 0.f, s1 = 0.f, s2 = 0.f, s3 = 0.f;
            #pragma unroll
            for (int n = 0; n < 8; ++n) {
                s0 += rlf(p, 4 * n + 0);
                s1 += rlf(p, 4 * n + 1);
                s2 += rlf(p, 4 * n + 2);
                s3 += rlf(p, 4 * n + 3);
            }
            float ss = (s0 + s1) + (s2 + s3);
            p = p / ss;
            C += (double)__logf(ss);
        }
        // tail i = 7..1 (slots 0..6 hold e[7..1])
        #pragma unroll
        for (int u = 0; u < 7; ++u) {
            int i = 7 - u;
            float pe = p * __expf(ef[u]);
            float q0 = 0.f, q1 = 0.f, q2 = 0.f, q3 = 0.f;
            #pragma unroll
            for (int n = 0; n < 8; ++n) {
                q0 = fmaf(rlf(pe, 4 * n + 0), Et[4 * n + 0], q0);
                q1 = fmaf(rlf(pe, 4 * n + 1), Et[4 * n + 1], q1);
                q2 = fmaf(rlf(pe, 4 * n + 2), Et[4 * n + 2], q2);
                q3 = fmaf(rlf(pe, 4 * n + 3), Et[4 * n + 3], q3);
            }
            float qq = (q0 + q1) + (q2 + q3);
            if (MBIT(i)) p = qq;
            if (tid < 32) pb[(size_t)((i - 1) * BATCH + b) * T + j] = p;
            if (tid == 0) Cb[(i - 1) * BATCH + b] = C;
        }
    } else {
        // ---- viterbi: exact (rlf(sc,n)+trv[n])+ej, pairwise first-wins tree ----
        float trv[32];
        #pragma unroll
        for (int n = 0; n < 32; ++n)
            trv[n] = trans[n * T + j];

        float sc = start[j] + e[(0 * BATCH + b) * T + j];

        float ef[8];
        #pragma unroll
        for (int u = 0; u < 8; ++u)
            ef[u] = e[(size_t)((1 + u) * BATCH + b) * T + j];

        for (int g = 0; g < 64; ++g) {     // 63 full groups + tail of 7
            int i0 = 1 + 8 * g;
            int lim = (g < 63) ? 8 : 7;
            #pragma unroll
            for (int u = 0; u < 8; ++u) {
                if (u >= lim) break;
                int i = i0 + u;
                float ej = ef[u];
                int inx = i + 8; inx = inx < SEQ ? inx : SEQ - 1;
                ef[u] = e[(size_t)(inx * BATCH + b) * T + j];
                float c_[32];
                #pragma unroll
                for (int n = 0; n < 32; ++n)
                    c_[n] = (rlf(sc, n) + trv[n]) + ej;
                float v1[16]; int i1[16];
                #pragma unroll
                for (int n = 0; n < 16; ++n) {
                    bool t = c_[2 * n] >= c_[2 * n + 1];
                    v1[n] = t ? c_[2 * n] : c_[2 * n + 1];
                    i1[n] = t ? 2 * n : 2 * n + 1;
                }
                float v2[8]; int i2[8];
                #pragma unroll
                for (int n = 0; n < 8; ++n) {
                    bool t = v1[2 * n] >= v1[2 * n + 1];
                    v2[n] = t ? v1[2 * n] : v1[2 * n + 1];
                    i2[n] = t ? i1[2 * n] : i1[2 * n + 1];
                }
                float v3[4]; int i3[4];
                #pragma unroll
                for (int n = 0; n < 4; ++n) {
                    bool t = v2[2 * n] >= v2[2 * n + 1];
                    v3[n] = t ? v2[2 * n] : v2[2 * n + 1];
                    i3[n] = t ? i2[2 * n] : i2[2 * n + 1];
                }
                float v4[2]; int i4[2];
                #pragma unroll
                for (int n = 0; n < 2; ++n) {
                    bool t = v3[2 * n] >= v3[2 * n + 1];
                    v4[n] = t ? v3[2 * n] : v3[2 * n + 1];
                    i4[n] = t ? i3[2 * n] : i3[2 * n + 1];
                }
                bool t = v4[0] >= v4[1];
                float best = t ? v4[0] : v4[1];
                int bi = t ? i4[0] : i4[1];

                if (tid < 32) hist[(i - 1) * T + j] = (unsigned char)bi;
                if (MBIT(i)) sc = best;
            }
        }
        // last = argmax_j(score + end), first index on ties
        float fs = sc + endp[j];
        int fj = j;
        #pragma unroll
        for (int d = 1; d < 32; d <<= 1) {
            float ov = __shfl_xor(fs, d);
            int oj = __shfl_xor(fj, d);
            if (ov > fs || (ov == fs && oj < fj)) { fs = ov; fj = oj; }
        }
        __syncthreads();
        if (tid == 0) {
            int tag = fj;
            tags_out[(SEQ - 1) * BATCH + b] = (float)tag;
            for (int i = SEQ - 2; i >= 0; --i) {
                tag = hist[i * T + tag];
                tags_out[i * BATCH + b] = (float)tag;
            }
        }
    }
}

// ---------------- probs = pa * pb * exp(Ca + Cb - z) ----------------
__global__ __launch_bounds__(256) void k_probs(const float* __restrict__ pa,
        const float* __restrict__ pb, const double* __restrict__ Ca,
        const double* __restrict__ Cb, const double* __restrict__ zd,
        float* __restrict__ out)
{
    int idx = blockIdx.x * 256 + threadIdx.x;   // float4 index, 524288 total
    int ib = idx >> 3;                          // (i*BATCH + b)
    int b = ib & (BATCH - 1);
    double ex = Ca[ib] + Cb[ib] - zd[b];
    double scl = exp(ex);
    float4 a = ((const float4*)pa)[idx];
    float4 c = ((const float4*)pb)[idx];
    float4 o;
    o.x = (float)((double)a.x * (double)c.x * scl);
    o.y = (float)((double)a.y * (double)c.y * scl);
    o.z = (float)((double)a.z * (double)c.z * scl);
    o.w = (float)((double)a.w * (double)c.w * scl);
    ((float4*)out)[idx] = o;
}

extern "C" void kernel_launch(void* const* d_in, const int* in_sizes, int n_in,
                              void* d_out, int out_size, void* d_ws, size_t ws_size,
                              hipStream_t stream) {
    const float* features = (const float*)d_in[0];
    const int*   mask     = (const int*)d_in[1];
    const float* W        = (const float*)d_in[2];
    const float* bias     = (const float*)d_in[3];
    const float* trans    = (const float*)d_in[4];
    const float* startp   = (const float*)d_in[5];
    const float* endp     = (const float*)d_in[6];

    char* ws = (char*)d_ws;
    double* Ca = (double*)(ws + 0);                      // 65536 doubles
    double* Cb = (double*)(ws + 524288);                 // 65536 doubles
    double* zd = (double*)(ws + 1048576);                // 128 doubles
    float*  Wt = (float*)(ws + 1049600);                 // 32768 floats
    float*  e  = (float*)(ws + 1180672);                 // 2097152 floats
    float*  pa = (float*)(ws + 9569280);                 // 2097152 floats
    float*  pb = (float*)(ws + 17957888);                // 2097152 floats

    float* probs_out = (float*)d_out;
    float* tags_out  = probs_out + (size_t)SEQ * BATCH * T;

    k_wt<<<128, 256, 0, stream>>>(W, Wt);
    k_emis<<<1024, 256, 0, stream>>>(features, Wt, bias, e);
    k_rec<<<384, 64, 0, stream>>>(e, mask, trans, startp, endp,
                                  pa, pb, Ca, Cb, zd, tags_out);
    k_probs<<<2048, 256, 0, stream>>>(pa, pb, Ca, Cb, zd, probs_out);
}

// Round 6
// 382.316 us; speedup vs baseline: 1.0017x; 1.0017x over previous
//
#include <hip/hip_runtime.h>

#define SEQ 512
#define BATCH 128
#define DIM 1024
#define T 32

__device__ __forceinline__ float rlf(float x, int n) {
    return __int_as_float(__builtin_amdgcn_readlane(__float_as_int(x), n));
}

// wave-uniform mask bit: 512 bits in 8 u64 (SGPR-resident), cselect tree + shift
__device__ __forceinline__ int mbit(unsigned long long m0, unsigned long long m1,
        unsigned long long m2, unsigned long long m3, unsigned long long m4,
        unsigned long long m5, unsigned long long m6, unsigned long long m7, int i) {
    int w = i >> 6;
    unsigned long long cm =
        (w < 4) ? ((w < 2) ? (w == 0 ? m0 : m1) : (w == 2 ? m2 : m3))
                : ((w < 6) ? (w == 4 ? m4 : m5) : (w == 6 ? m6 : m7));
    return (int)((cm >> (i & 63)) & 1ULL);
}

#define LOAD_MASKS() \
    unsigned long long m0 = __ballot(mask[(0 * 64 + tid) * BATCH + b] != 0); \
    unsigned long long m1 = __ballot(mask[(1 * 64 + tid) * BATCH + b] != 0); \
    unsigned long long m2 = __ballot(mask[(2 * 64 + tid) * BATCH + b] != 0); \
    unsigned long long m3 = __ballot(mask[(3 * 64 + tid) * BATCH + b] != 0); \
    unsigned long long m4 = __ballot(mask[(4 * 64 + tid) * BATCH + b] != 0); \
    unsigned long long m5 = __ballot(mask[(5 * 64 + tid) * BATCH + b] != 0); \
    unsigned long long m6 = __ballot(mask[(6 * 64 + tid) * BATCH + b] != 0); \
    unsigned long long m7 = __ballot(mask[(7 * 64 + tid) * BATCH + b] != 0);

#define MBIT(i) mbit(m0, m1, m2, m3, m4, m5, m6, m7, (i))

// ---------------- W transpose: Wt[d][t] = W[t][d] ----------------
__global__ void k_wt(const float* __restrict__ W, float* __restrict__ Wt)
{
    int idx = blockIdx.x * 256 + threadIdx.x;   // 32768 total
    if (idx >= DIM * T) return;
    int d = idx >> 5, t = idx & 31;
    Wt[idx] = W[t * DIM + d];
}

// ---------------- emissions (unchanged) ----------------
__global__ __launch_bounds__(256) void k_emis(const float* __restrict__ A,
        const float* __restrict__ Wt, const float* __restrict__ bias,
        float* __restrict__ e)
{
    __shared__ float lds[64 * 37];
    int tid = threadIdx.x;
    int row0 = blockIdx.x * 64;
    int row = tid & 63;
    int grp = __builtin_amdgcn_readfirstlane(tid >> 6);   // 0..3, wave-uniform
    int q = tid & 7;
    int rb = tid >> 3;

    float acc[8];
    #pragma unroll
    for (int t = 0; t < 8; ++t) acc[t] = bias[grp * 8 + t];

    const float* A0 = &A[(size_t)(row0 + rb) * DIM];
    const float* A1 = &A[(size_t)(row0 + rb + 32) * DIM];

    float4 v0 = *(const float4*)&A0[q * 4];
    float4 v1 = *(const float4*)&A1[q * 4];

    for (int ck = 0; ck < 32; ++ck) {
        lds[rb * 37 + q * 4 + 0] = v0.x;
        lds[rb * 37 + q * 4 + 1] = v0.y;
        lds[rb * 37 + q * 4 + 2] = v0.z;
        lds[rb * 37 + q * 4 + 3] = v0.w;
        lds[(rb + 32) * 37 + q * 4 + 0] = v1.x;
        lds[(rb + 32) * 37 + q * 4 + 1] = v1.y;
        lds[(rb + 32) * 37 + q * 4 + 2] = v1.z;
        lds[(rb + 32) * 37 + q * 4 + 3] = v1.w;
        __syncthreads();
        if (ck < 31) {
            v0 = *(const float4*)&A0[(ck + 1) * 32 + q * 4];
            v1 = *(const float4*)&A1[(ck + 1) * 32 + q * 4];
        }
        #pragma unroll
        for (int d = 0; d < 32; ++d) {
            float av = lds[row * 37 + d];
            const float* wrow = &Wt[(ck * 32 + d) * T + grp * 8];
            #pragma unroll
            for (int t = 0; t < 8; ++t)
                acc[t] = fmaf(av, wrow[t], acc[t]);
        }
        __syncthreads();
    }

    float4* eo = (float4*)&e[(size_t)(row0 + row) * T + grp * 8];
    float4 o0, o1;
    o0.x = acc[0]; o0.y = acc[1]; o0.z = acc[2]; o0.w = acc[3];
    o1.x = acc[4]; o1.y = acc[5]; o1.z = acc[6]; o1.w = acc[7];
    eo[0] = o0; eo[1] = o1;
}

// ---------------- recursions: role 0=alpha(+z), 1=beta, 2=viterbi ----------------
// __launch_bounds__(64, 1): 1 wave/EU minimum -> up to 512 VGPRs, so the
// per-lane tables (Et[32]/trv[32]) and the 8-slot e-ring stay in registers
// instead of spilling to scratch (rounds 3-5 were stuck at VGPR_Count=68).
__global__ __launch_bounds__(64, 1) void k_rec(const float* __restrict__ e,
        const int* __restrict__ mask,
        const float* __restrict__ trans,
        const float* __restrict__ start,
        const float* __restrict__ endp,
        float* __restrict__ pa, float* __restrict__ pb,
        double* __restrict__ Ca, double* __restrict__ Cb,
        double* __restrict__ zd,
        float* __restrict__ tags_out)
{
    __shared__ unsigned char hist[(SEQ - 1) * T];   // viterbi history (role 2 only)

    int role = blockIdx.x >> 7;     // /128
    int b    = blockIdx.x & 127;
    int tid  = threadIdx.x;
    int j    = tid & 31;            // state (both halves duplicate)

    LOAD_MASKS();

    if (role == 0) {
        // ---- alpha: Et[n] = exp(trans[n][j]) ----
        float Et[32];
        #pragma unroll
        for (int n = 0; n < 32; ++n)
            Et[n] = __expf(trans[n * T + j]);

        float a0 = e[(0 * BATCH + b) * T + j] + start[j];
        float m = a0;
        #pragma unroll
        for (int d = 1; d < 32; d <<= 1) m = fmaxf(m, __shfl_xor(m, d));
        float v = __expf(a0 - m);
        float s = v;
        #pragma unroll
        for (int d = 1; d < 32; d <<= 1) s += __shfl_xor(s, d);
        float p = v / s;
        double C = (double)m + (double)__logf(s);
        if (tid < 32) pa[(size_t)(0 * BATCH + b) * T + j] = p;
        if (tid == 0) Ca[0 * BATCH + b] = C;

        float ef[8];
        #pragma unroll
        for (int u = 0; u < 8; ++u)
            ef[u] = e[(size_t)((1 + u) * BATCH + b) * T + j];

        for (int g = 0; g < 63; ++g) {
            int i0 = 1 + 8 * g;
            #pragma unroll
            for (int u = 0; u < 8; ++u) {
                int i = i0 + u;
                float ee = __expf(ef[u]);
                int inx = i + 8; inx = inx < SEQ ? inx : SEQ - 1;
                ef[u] = e[(size_t)(inx * BATCH + b) * T + j];   // refill slot (8 ahead)
                float q0 = 0.f, q1 = 0.f, q2 = 0.f, q3 = 0.f;
                #pragma unroll
                for (int n = 0; n < 8; ++n) {
                    q0 = fmaf(rlf(p, 4 * n + 0), Et[4 * n + 0], q0);
                    q1 = fmaf(rlf(p, 4 * n + 1), Et[4 * n + 1], q1);
                    q2 = fmaf(rlf(p, 4 * n + 2), Et[4 * n + 2], q2);
                    q3 = fmaf(rlf(p, 4 * n + 3), Et[4 * n + 3], q3);
                }
                float vv = ((q0 + q1) + (q2 + q3)) * ee;
                if (MBIT(i)) p = vv;
                if (tid < 32) pa[(size_t)(i * BATCH + b) * T + j] = p;
                if (tid == 0) Ca[i * BATCH + b] = C;
            }
            float s0 = 0.f, s1 = 0.f, s2 = 0.f, s3 = 0.f;
            #pragma unroll
            for (int n = 0; n < 8; ++n) {
                s0 += rlf(p, 4 * n + 0);
                s1 += rlf(p, 4 * n + 1);
                s2 += rlf(p, 4 * n + 2);
                s3 += rlf(p, 4 * n + 3);
            }
            float ss = (s0 + s1) + (s2 + s3);
            p = p / ss;
            C += (double)__logf(ss);
        }
        // tail i = 505..511 (slots 0..6)
        #pragma unroll
        for (int u = 0; u < 7; ++u) {
            int i = 505 + u;
            float ee = __expf(ef[u]);
            float q0 = 0.f, q1 = 0.f, q2 = 0.f, q3 = 0.f;
            #pragma unroll
            for (int n = 0; n < 8; ++n) {
                q0 = fmaf(rlf(p, 4 * n + 0), Et[4 * n + 0], q0);
                q1 = fmaf(rlf(p, 4 * n + 1), Et[4 * n + 1], q1);
                q2 = fmaf(rlf(p, 4 * n + 2), Et[4 * n + 2], q2);
                q3 = fmaf(rlf(p, 4 * n + 3), Et[4 * n + 3], q3);
            }
            float vv = ((q0 + q1) + (q2 + q3)) * ee;
            if (MBIT(i)) p = vv;
            if (tid < 32) pa[(size_t)(i * BATCH + b) * T + j] = p;
            if (tid == 0) Ca[i * BATCH + b] = C;
        }
        // fused z[b]
        float sz = p * __expf(endp[j]);
        #pragma unroll
        for (int d = 1; d < 32; d <<= 1) sz += __shfl_xor(sz, d);
        if (tid == 0) zd[b] = C + (double)__logf(sz);
    } else if (role == 1) {
        // ---- beta: Et[n] = exp(trans[j][n]) ----
        float Et[32];
        #pragma unroll
        for (int n = 0; n < 32; ++n)
            Et[n] = __expf(trans[j * T + n]);

        float v0 = endp[j];
        float m = v0;
        #pragma unroll
        for (int d = 1; d < 32; d <<= 1) m = fmaxf(m, __shfl_xor(m, d));
        float v = __expf(v0 - m);
        float s = v;
        #pragma unroll
        for (int d = 1; d < 32; d <<= 1) s += __shfl_xor(s, d);
        float p = v / s;
        double C = (double)m + (double)__logf(s);
        if (tid < 32) pb[(size_t)((SEQ - 1) * BATCH + b) * T + j] = p;
        if (tid == 0) Cb[(SEQ - 1) * BATCH + b] = C;

        float ef[8];
        #pragma unroll
        for (int u = 0; u < 8; ++u)
            ef[u] = e[(size_t)((SEQ - 1 - u) * BATCH + b) * T + j];

        for (int g = 0; g < 63; ++g) {
            int i0 = SEQ - 1 - 8 * g;
            #pragma unroll
            for (int u = 0; u < 8; ++u) {
                int i = i0 - u;                       // 511 down to 8
                float ee = __expf(ef[u]);
                int inx = i - 8;                      // >= 0 always
                ef[u] = e[(size_t)(inx * BATCH + b) * T + j];
                float pe = p * ee;
                float q0 = 0.f, q1 = 0.f, q2 = 0.f, q3 = 0.f;
                #pragma unroll
                for (int n = 0; n < 8; ++n) {
                    q0 = fmaf(rlf(pe, 4 * n + 0), Et[4 * n + 0], q0);
                    q1 = fmaf(rlf(pe, 4 * n + 1), Et[4 * n + 1], q1);
                    q2 = fmaf(rlf(pe, 4 * n + 2), Et[4 * n + 2], q2);
                    q3 = fmaf(rlf(pe, 4 * n + 3), Et[4 * n + 3], q3);
                }
                float qq = (q0 + q1) + (q2 + q3);
                if (MBIT(i)) p = qq;
                if (tid < 32) pb[(size_t)((i - 1) * BATCH + b) * T + j] = p;
                if (tid == 0) Cb[(i - 1) * BATCH + b] = C;
            }
            float s0 = 0.f, s1 = 0.f, s2 = 0.f, s3 = 0.f;
            #pragma unroll
            for (int n = 0; n < 8; ++n) {
                s0 += rlf(p, 4 * n + 0);
                s1 += rlf(p, 4 * n + 1);
                s2 += rlf(p, 4 * n + 2);
                s3 += rlf(p, 4 * n + 3);
            }
            float ss = (s0 + s1) + (s2 + s3);
            p = p / ss;
            C += (double)__logf(ss);
        }
        // tail i = 7..1 (slots 0..6 hold e[7..1])
        #pragma unroll
        for (int u = 0; u < 7; ++u) {
            int i = 7 - u;
            float pe = p * __expf(ef[u]);
            float q0 = 0.f, q1 = 0.f, q2 = 0.f, q3 = 0.f;
            #pragma unroll
            for (int n = 0; n < 8; ++n) {
                q0 = fmaf(rlf(pe, 4 * n + 0), Et[4 * n + 0], q0);
                q1 = fmaf(rlf(pe, 4 * n + 1), Et[4 * n + 1], q1);
                q2 = fmaf(rlf(pe, 4 * n + 2), Et[4 * n + 2], q2);
                q3 = fmaf(rlf(pe, 4 * n + 3), Et[4 * n + 3], q3);
            }
            float qq = (q0 + q1) + (q2 + q3);
            if (MBIT(i)) p = qq;
            if (tid < 32) pb[(size_t)((i - 1) * BATCH + b) * T + j] = p;
            if (tid == 0) Cb[(i - 1) * BATCH + b] = C;
        }
    } else {
        // ---- viterbi: exact (rlf(sc,n)+trv[n])+ej, pairwise first-wins tree ----
        float trv[32];
        #pragma unroll
        for (int n = 0; n < 32; ++n)
            trv[n] = trans[n * T + j];

        float sc = start[j] + e[(0 * BATCH + b) * T + j];

        float ef[8];
        #pragma unroll
        for (int u = 0; u < 8; ++u)
            ef[u] = e[(size_t)((1 + u) * BATCH + b) * T + j];

        for (int g = 0; g < 64; ++g) {     // 63 full groups + tail of 7
            int i0 = 1 + 8 * g;
            int lim = (g < 63) ? 8 : 7;
            #pragma unroll
            for (int u = 0; u < 8; ++u) {
                if (u >= lim) break;
                int i = i0 + u;
                float ej = ef[u];
                int inx = i + 8; inx = inx < SEQ ? inx : SEQ - 1;
                ef[u] = e[(size_t)(inx * BATCH + b) * T + j];
                float c_[32];
                #pragma unroll
                for (int n = 0; n < 32; ++n)
                    c_[n] = (rlf(sc, n) + trv[n]) + ej;
                float v1[16]; int i1[16];
                #pragma unroll
                for (int n = 0; n < 16; ++n) {
                    bool t = c_[2 * n] >= c_[2 * n + 1];
                    v1[n] = t ? c_[2 * n] : c_[2 * n + 1];
                    i1[n] = t ? 2 * n : 2 * n + 1;
                }
                float v2[8]; int i2[8];
                #pragma unroll
                for (int n = 0; n < 8; ++n) {
                    bool t = v1[2 * n] >= v1[2 * n + 1];
                    v2[n] = t ? v1[2 * n] : v1[2 * n + 1];
                    i2[n] = t ? i1[2 * n] : i1[2 * n + 1];
                }
                float v3[4]; int i3[4];
                #pragma unroll
                for (int n = 0; n < 4; ++n) {
                    bool t = v2[2 * n] >= v2[2 * n + 1];
                    v3[n] = t ? v2[2 * n] : v2[2 * n + 1];
                    i3[n] = t ? i2[2 * n] : i2[2 * n + 1];
                }
                float v4[2]; int i4[2];
                #pragma unroll
                for (int n = 0; n < 2; ++n) {
                    bool t = v3[2 * n] >= v3[2 * n + 1];
                    v4[n] = t ? v3[2 * n] : v3[2 * n + 1];
                    i4[n] = t ? i3[2 * n] : i3[2 * n + 1];
                }
                bool t = v4[0] >= v4[1];
                float best = t ? v4[0] : v4[1];
                int bi = t ? i4[0] : i4[1];

                if (tid < 32) hist[(i - 1) * T + j] = (unsigned char)bi;
                if (MBIT(i)) sc = best;
            }
        }
        // last = argmax_j(score + end), first index on ties
        float fs = sc + endp[j];
        int fj = j;
        #pragma unroll
        for (int d = 1; d < 32; d <<= 1) {
            float ov = __shfl_xor(fs, d);
            int oj = __shfl_xor(fj, d);
            if (ov > fs || (ov == fs && oj < fj)) { fs = ov; fj = oj; }
        }
        __syncthreads();
        if (tid == 0) {
            int tag = fj;
            tags_out[(SEQ - 1) * BATCH + b] = (float)tag;
            for (int i = SEQ - 2; i >= 0; --i) {
                tag = hist[i * T + tag];
                tags_out[i * BATCH + b] = (float)tag;
            }
        }
    }
}

// ---------------- probs = pa * pb * exp(Ca + Cb - z) ----------------
__global__ __launch_bounds__(256) void k_probs(const float* __restrict__ pa,
        const float* __restrict__ pb, const double* __restrict__ Ca,
        const double* __restrict__ Cb, const double* __restrict__ zd,
        float* __restrict__ out)
{
    int idx = blockIdx.x * 256 + threadIdx.x;   // float4 index, 524288 total
    int ib = idx >> 3;                          // (i*BATCH + b)
    int b = ib & (BATCH - 1);
    double ex = Ca[ib] + Cb[ib] - zd[b];
    double scl = exp(ex);
    float4 a = ((const float4*)pa)[idx];
    float4 c = ((const float4*)pb)[idx];
    float4 o;
    o.x = (float)((double)a.x * (double)c.x * scl);
    o.y = (float)((double)a.y * (double)c.y * scl);
    o.z = (float)((double)a.z * (double)c.z * scl);
    o.w = (float)((double)a.w * (double)c.w * scl);
    ((float4*)out)[idx] = o;
}

extern "C" void kernel_launch(void* const* d_in, const int* in_sizes, int n_in,
                              void* d_out, int out_size, void* d_ws, size_t ws_size,
                              hipStream_t stream) {
    const float* features = (const float*)d_in[0];
    const int*   mask     = (const int*)d_in[1];
    const float* W        = (const float*)d_in[2];
    const float* bias     = (const float*)d_in[3];
    const float* trans    = (const float*)d_in[4];
    const float* startp   = (const float*)d_in[5];
    const float* endp     = (const float*)d_in[6];

    char* ws = (char*)d_ws;
    double* Ca = (double*)(ws + 0);                      // 65536 doubles
    double* Cb = (double*)(ws + 524288);                 // 65536 doubles
    double* zd = (double*)(ws + 1048576);                // 128 doubles
    float*  Wt = (float*)(ws + 1049600);                 // 32768 floats
    float*  e  = (float*)(ws + 1180672);                 // 2097152 floats
    float*  pa = (float*)(ws + 9569280);                 // 2097152 floats
    float*  pb = (float*)(ws + 17957888);                // 2097152 floats

    float* probs_out = (float*)d_out;
    float* tags_out  = probs_out + (size_t)SEQ * BATCH * T;

    k_wt<<<128, 256, 0, stream>>>(W, Wt);
    k_emis<<<1024, 256, 0, stream>>>(features, Wt, bias, e);
    k_rec<<<384, 64, 0, stream>>>(e, mask, trans, startp, endp,
                                  pa, pb, Ca, Cb, zd, tags_out);
    k_probs<<<2048, 256, 0, stream>>>(pa, pb, Ca, Cb, zd, probs_out);
}